// Round 1
// baseline (409.180 us; speedup 1.0000x reference)
//
#include <hip/hip_runtime.h>

#define Bn 16
#define Ln 128
#define Hn 256
#define Dn 256

// Output layout (flat fp32 concat, reference return order)
#define OFF_MASK   0          // (B,L,L) 262144
#define OFF_SMP    262144     // (B,L,L) 262144
#define OFF_ENT    524288     // (B,L,L) 262144
#define OFF_GRAPH  786432     // (L,L)   16384
#define OFF_LSE    802816     // scalar
#define OFF_EREG   802817     // (B,)    16

static __device__ __forceinline__ unsigned rotl32(unsigned x, int r) {
  return (x << r) | (x >> (32 - r));
}

// Threefry-2x32, 20 rounds, key = (0,1)  [jax.random.key(1)]
// Partitionable random-bits path: counter = (hi, lo), 32-bit output = y0 ^ y1.
static __device__ __forceinline__ unsigned threefry_bits(unsigned c_hi, unsigned c_lo) {
  const unsigned ks0 = 0u, ks1 = 1u;
  const unsigned ks2 = 0u ^ 1u ^ 0x1BD11BDAu;
  unsigned x0 = c_hi + ks0;
  unsigned x1 = c_lo + ks1;
  // group 1: rotations [13,15,26,6]
  x0 += x1; x1 = rotl32(x1, 13); x1 ^= x0;
  x0 += x1; x1 = rotl32(x1, 15); x1 ^= x0;
  x0 += x1; x1 = rotl32(x1, 26); x1 ^= x0;
  x0 += x1; x1 = rotl32(x1, 6);  x1 ^= x0;
  x0 += ks1; x1 += ks2 + 1u;
  // group 2: [17,29,16,24]
  x0 += x1; x1 = rotl32(x1, 17); x1 ^= x0;
  x0 += x1; x1 = rotl32(x1, 29); x1 ^= x0;
  x0 += x1; x1 = rotl32(x1, 16); x1 ^= x0;
  x0 += x1; x1 = rotl32(x1, 24); x1 ^= x0;
  x0 += ks2; x1 += ks0 + 2u;
  // group 3: [13,15,26,6]
  x0 += x1; x1 = rotl32(x1, 13); x1 ^= x0;
  x0 += x1; x1 = rotl32(x1, 15); x1 ^= x0;
  x0 += x1; x1 = rotl32(x1, 26); x1 ^= x0;
  x0 += x1; x1 = rotl32(x1, 6);  x1 ^= x0;
  x0 += ks0; x1 += ks1 + 3u;
  // group 4: [17,29,16,24]
  x0 += x1; x1 = rotl32(x1, 17); x1 ^= x0;
  x0 += x1; x1 = rotl32(x1, 29); x1 ^= x0;
  x0 += x1; x1 = rotl32(x1, 16); x1 ^= x0;
  x0 += x1; x1 = rotl32(x1, 24); x1 ^= x0;
  x0 += ks1; x1 += ks2 + 4u;
  // group 5: [13,15,26,6]
  x0 += x1; x1 = rotl32(x1, 13); x1 ^= x0;
  x0 += x1; x1 = rotl32(x1, 15); x1 ^= x0;
  x0 += x1; x1 = rotl32(x1, 26); x1 ^= x0;
  x0 += x1; x1 = rotl32(x1, 6);  x1 ^= x0;
  x0 += ks2; x1 += ks0 + 5u;
  return x0 ^ x1;
}

static __device__ __forceinline__ double softplus_d(double x) {
  // jax.nn.softplus == logaddexp(x, 0) == max(x,0) + log1p(exp(-|x|)); exact at |x|=1e8
  return fmax(x, 0.0) + log1p(exp(-fabs(x)));
}

__global__ void zero_kernel(float* __restrict__ out, double* __restrict__ ws_acc) {
  int t = blockIdx.x * blockDim.x + threadIdx.x;
  if (t < Ln * Ln) out[OFF_GRAPH + t] = 0.0f;
  if (t < 17) ws_acc[t] = 0.0;
}

// fp64 projections: dl = enc @ W_l, dr = enc @ W_r   (row = b*L+i, one block/row)
__global__ void proj_kernel(const float* __restrict__ enc,
                            const float* __restrict__ Wl,
                            const float* __restrict__ Wr,
                            double* __restrict__ dl,
                            double* __restrict__ dr) {
  int row = blockIdx.x;      // 0..2047
  int d = threadIdx.x;       // 0..255
  __shared__ float encS[Hn];
  encS[d] = enc[(size_t)row * Hn + d];
  __syncthreads();
  double al = 0.0, ar = 0.0;
  for (int h = 0; h < Hn; ++h) {
    double e = (double)encS[h];
    al += e * (double)Wl[h * Dn + d];
    ar += e * (double)Wr[h * Dn + d];
  }
  dl[(size_t)row * Dn + d] = al;
  dr[(size_t)row * Dn + d] = ar;
}

// One block per (b,i); 256 threads; j in tiles of 16.
__global__ void pair_kernel(const double* __restrict__ dl,
                            const double* __restrict__ dr,
                            const float* __restrict__ U,
                            const float* __restrict__ bias,
                            float* __restrict__ out,
                            double* __restrict__ ws_acc) {
  int blk = blockIdx.x;          // b*L + i
  int b = blk >> 7;              // /128
  int i = blk & 127;
  int t = threadIdx.x;           // 0..255

  __shared__ double dlS[Dn];
  __shared__ double US[Dn];
  __shared__ double drS[16 * Dn];
  __shared__ double pS[256];
  __shared__ double red[32];

  dlS[t] = dl[(size_t)blk * Dn + t];
  US[t] = (double)U[t];
  double biasv = (double)bias[0];

  double ent_acc = 0.0;   // only meaningful for t<16
  double lse_acc = 0.0;

  for (int j0 = 0; j0 < Ln; j0 += 16) {
    __syncthreads();  // prior tile fully consumed (drS reads + pS epilogue reads)
    const double* drg = dr + ((size_t)b * Ln + j0) * Dn;
#pragma unroll
    for (int k = 0; k < 16; ++k)
      drS[k * 256 + t] = drg[k * 256 + t];
    __syncthreads();

    int jj = t >> 4;     // local j 0..15
    int dp = t & 15;     // d-chunk 0..15
    const double* drow = &drS[jj * Dn];
    double s = 0.0;
#pragma unroll
    for (int k = 0; k < 16; ++k) {
      int d = dp * 16 + k;
      s += tanh(dlS[d] + drow[d]) * US[d];
    }
    pS[t] = s;
    __syncthreads();

    if (t < 16) {
      int j = j0 + t;
      double tot = 0.0;
#pragma unroll
      for (int k = 0; k < 16; ++k) tot += pS[t * 16 + k];
      double l = tot + biasv - ((j == i) ? 1.0e8 : 0.0);
      double p = 1.0 / (1.0 + exp(-l));       // sigmoid; exact 0 on diagonal
      unsigned n = (unsigned)blk * 128u + (unsigned)j;   // flat (b,i,j) index
      unsigned bits = threefry_bits(0u, n);
      float u = __uint_as_float((bits >> 9) | 0x3f800000u) - 1.0f;
      float pf = (float)p;
      float smp = (u < pf) ? 1.0f : 0.0f;
      double sp_pos = softplus_d(l);
      double sp_neg = softplus_d(-l);
      double ent = p * sp_neg + (1.0 - p) * sp_pos;
      size_t idx = (size_t)blk * Ln + j;
      out[OFF_MASK + idx] = (float)l;
      out[OFF_SMP + idx] = smp;
      out[OFF_ENT + idx] = (float)ent;
      atomicAdd(&out[OFF_GRAPH + i * Ln + j], smp * 0.0625f);  // mean over B=16, exact
      ent_acc += ent;
      lse_acc += sp_pos - l * (double)smp;
    }
  }

  __syncthreads();
  if (t < 16) { red[t] = ent_acc; red[16 + t] = lse_acc; }
  __syncthreads();
  if (t == 0) {
    double es = 0.0, ls = 0.0;
#pragma unroll
    for (int k = 0; k < 16; ++k) { es += red[k]; ls += red[16 + k]; }
    atomicAdd(&ws_acc[b], es);
    atomicAdd(&ws_acc[16], ls);
  }
}

__global__ void finalize_kernel(const double* __restrict__ ws_acc, float* __restrict__ out) {
  int t = threadIdx.x;
  if (t == 0) out[OFF_LSE] = (float)(ws_acc[16] / (double)(Bn * Ln * Ln));
  if (t < Bn) out[OFF_EREG + t] = (float)(ws_acc[t] / (double)(Ln * Ln));
}

extern "C" void kernel_launch(void* const* d_in, const int* in_sizes, int n_in,
                              void* d_out, int out_size, void* d_ws, size_t ws_size,
                              hipStream_t stream) {
  const float* enc = (const float*)d_in[0];
  const float* Wl = (const float*)d_in[1];
  const float* Wr = (const float*)d_in[2];
  const float* U = (const float*)d_in[3];
  const float* bias = (const float*)d_in[4];
  float* out = (float*)d_out;

  // ws layout: dl (2048*256 dbl), dr (2048*256 dbl), accumulators (17 dbl)
  double* dl = (double*)d_ws;
  double* dr = dl + (size_t)Bn * Ln * Dn;
  double* ws_acc = dr + (size_t)Bn * Ln * Dn;

  zero_kernel<<<64, 256, 0, stream>>>(out, ws_acc);
  proj_kernel<<<Bn * Ln, Dn, 0, stream>>>(enc, Wl, Wr, dl, dr);
  pair_kernel<<<Bn * Ln, 256, 0, stream>>>(dl, dr, U, bias, out, ws_acc);
  finalize_kernel<<<1, 64, 0, stream>>>(ws_acc, out);
}

// Round 2
// 173.422 us; speedup vs baseline: 2.3594x; 2.3594x over previous
//
#include <hip/hip_runtime.h>

#define Bn 16
#define Ln 128
#define Hn 256
#define Dn 256

// Output layout (flat fp32 concat, reference return order)
#define OFF_MASK   0          // (B,L,L) 262144
#define OFF_SMP    262144     // (B,L,L) 262144
#define OFF_ENT    524288     // (B,L,L) 262144
#define OFF_GRAPH  786432     // (L,L)   16384
#define OFF_LSE    802816     // scalar
#define OFF_EREG   802817     // (B,)    16

static __device__ __forceinline__ unsigned rotl32(unsigned x, int r) {
  return (x << r) | (x >> (32 - r));
}

// Threefry-2x32, 20 rounds, key = (0,1)  [jax.random.key(1)], partitionable
// random-bits path: counter = (hi=0, lo=flat_index), output = y0 ^ y1.
static __device__ __forceinline__ unsigned threefry_bits(unsigned c_hi, unsigned c_lo) {
  const unsigned ks0 = 0u, ks1 = 1u;
  const unsigned ks2 = 0u ^ 1u ^ 0x1BD11BDAu;
  unsigned x0 = c_hi + ks0;
  unsigned x1 = c_lo + ks1;
  x0 += x1; x1 = rotl32(x1, 13); x1 ^= x0;
  x0 += x1; x1 = rotl32(x1, 15); x1 ^= x0;
  x0 += x1; x1 = rotl32(x1, 26); x1 ^= x0;
  x0 += x1; x1 = rotl32(x1, 6);  x1 ^= x0;
  x0 += ks1; x1 += ks2 + 1u;
  x0 += x1; x1 = rotl32(x1, 17); x1 ^= x0;
  x0 += x1; x1 = rotl32(x1, 29); x1 ^= x0;
  x0 += x1; x1 = rotl32(x1, 16); x1 ^= x0;
  x0 += x1; x1 = rotl32(x1, 24); x1 ^= x0;
  x0 += ks2; x1 += ks0 + 2u;
  x0 += x1; x1 = rotl32(x1, 13); x1 ^= x0;
  x0 += x1; x1 = rotl32(x1, 15); x1 ^= x0;
  x0 += x1; x1 = rotl32(x1, 26); x1 ^= x0;
  x0 += x1; x1 = rotl32(x1, 6);  x1 ^= x0;
  x0 += ks0; x1 += ks1 + 3u;
  x0 += x1; x1 = rotl32(x1, 17); x1 ^= x0;
  x0 += x1; x1 = rotl32(x1, 29); x1 ^= x0;
  x0 += x1; x1 = rotl32(x1, 16); x1 ^= x0;
  x0 += x1; x1 = rotl32(x1, 24); x1 ^= x0;
  x0 += ks1; x1 += ks2 + 4u;
  x0 += x1; x1 = rotl32(x1, 13); x1 ^= x0;
  x0 += x1; x1 = rotl32(x1, 15); x1 ^= x0;
  x0 += x1; x1 = rotl32(x1, 26); x1 ^= x0;
  x0 += x1; x1 = rotl32(x1, 6);  x1 ^= x0;
  x0 += ks2; x1 += ks0 + 5u;
  return x0 ^ x1;
}

static __device__ __forceinline__ float softplus_f(float x) {
  // max(x,0) + log1p(exp(-|x|)); exact at |x|=1e8 (exp(-1e8)=0)
  return fmaxf(x, 0.0f) + log1pf(__expf(-fabsf(x)));
}

static __device__ __forceinline__ float fast_tanh(float x) {
  // tanh(x) = 2/(1+e^{-2x}) - 1; saturates correctly for |x| large
  float e = __expf(-2.0f * x);
  float r = __builtin_amdgcn_rcpf(1.0f + e);
  return fmaf(2.0f, r, -1.0f);
}

__global__ void zero_kernel(float* __restrict__ out, double* __restrict__ ws_acc) {
  int t = blockIdx.x * blockDim.x + threadIdx.x;
  if (t < Ln * Ln) out[OFF_GRAPH + t] = 0.0f;
  if (t < 17) ws_acc[t] = 0.0;
}

// fp32 projections, 8 rows per block: dl = enc @ W_l, dr = enc @ W_r
__global__ void proj_kernel(const float* __restrict__ enc,
                            const float* __restrict__ Wl,
                            const float* __restrict__ Wr,
                            float* __restrict__ dl,
                            float* __restrict__ dr) {
  int r0 = blockIdx.x * 8;     // 256 blocks x 8 rows = 2048 rows
  int d = threadIdx.x;         // 0..255
  __shared__ float encS[8][Hn];
  float4* encS4 = (float4*)encS;
  const float4* encg = (const float4*)(enc + (size_t)r0 * Hn);
  encS4[d] = encg[d];
  encS4[d + 256] = encg[d + 256];
  __syncthreads();
  float al[8], ar[8];
#pragma unroll
  for (int r = 0; r < 8; ++r) { al[r] = 0.0f; ar[r] = 0.0f; }
  for (int h4 = 0; h4 < Hn / 4; ++h4) {
    float4 e[8];
#pragma unroll
    for (int r = 0; r < 8; ++r) e[r] = ((const float4*)encS[r])[h4];
#pragma unroll
    for (int q = 0; q < 4; ++q) {
      int h = h4 * 4 + q;
      float wl = Wl[h * Dn + d];
      float wr = Wr[h * Dn + d];
#pragma unroll
      for (int r = 0; r < 8; ++r) {
        float ev = (q == 0) ? e[r].x : (q == 1) ? e[r].y : (q == 2) ? e[r].z : e[r].w;
        al[r] = fmaf(ev, wl, al[r]);
        ar[r] = fmaf(ev, wr, ar[r]);
      }
    }
  }
#pragma unroll
  for (int r = 0; r < 8; ++r) {
    dl[(size_t)(r0 + r) * Dn + d] = al[r];
    dr[(size_t)(r0 + r) * Dn + d] = ar[r];
  }
}

// One block per (b,i); 256 threads. Thread (jj = t&15, dp = t>>4) owns
// d-slice [dp*16, dp*16+16) (dl,U reg-cached) and j = tile*16+jj per tile.
// dr read directly from global (L2-resident, 2 MB/b working set shared by
// 128 i-blocks). No barriers in the main loop; one pS spill + epilogue.
__global__ void pair_kernel(const float* __restrict__ dl,
                            const float* __restrict__ dr,
                            const float* __restrict__ U,
                            const float* __restrict__ bias,
                            float* __restrict__ out,
                            double* __restrict__ ws_acc) {
  int blk = blockIdx.x;          // b*L + i
  int b = blk >> 7;
  int i = blk & 127;
  int t = threadIdx.x;
  int jj = t & 15;
  int dp = t >> 4;

  __shared__ float pS[16 * 256];   // [tile][dp][jj]
  __shared__ float redS[4];

  // register-cache dl chunk and U chunk (fixed per thread)
  float dlr[16], Ur[16];
  {
    const float4* dl4 = (const float4*)(dl + (size_t)blk * Dn + dp * 16);
    const float4* U4 = (const float4*)(U + dp * 16);
#pragma unroll
    for (int q = 0; q < 4; ++q) {
      float4 a = dl4[q];
      float4 u = U4[q];
      dlr[4 * q + 0] = a.x; dlr[4 * q + 1] = a.y; dlr[4 * q + 2] = a.z; dlr[4 * q + 3] = a.w;
      Ur[4 * q + 0] = u.x;  Ur[4 * q + 1] = u.y;  Ur[4 * q + 2] = u.z;  Ur[4 * q + 3] = u.w;
    }
  }

  const float* drt = dr + (size_t)b * Ln * Dn + (size_t)jj * Dn + dp * 16;
#pragma unroll 4
  for (int tl = 0; tl < 16; ++tl) {
    const float4* drp = (const float4*)(drt + (size_t)tl * 16 * Dn);
    float a = 0.0f;
#pragma unroll
    for (int q = 0; q < 4; ++q) {
      float4 v = drp[q];
      a = fmaf(fast_tanh(dlr[4 * q + 0] + v.x), Ur[4 * q + 0], a);
      a = fmaf(fast_tanh(dlr[4 * q + 1] + v.y), Ur[4 * q + 1], a);
      a = fmaf(fast_tanh(dlr[4 * q + 2] + v.z), Ur[4 * q + 2], a);
      a = fmaf(fast_tanh(dlr[4 * q + 3] + v.w), Ur[4 * q + 3], a);
    }
    pS[tl * 256 + dp * 16 + jj] = a;
  }
  __syncthreads();

  float ent_v = 0.0f, lse_v = 0.0f;
  if (t < Ln) {
    int j = t;
    const float* ps = &pS[(j >> 4) * 256 + (j & 15)];
    float tot = 0.0f;
#pragma unroll
    for (int k = 0; k < 16; ++k) tot += ps[k * 16];
    float l = tot + bias[0] - ((j == i) ? 1.0e8f : 0.0f);
    float e = __expf(-l);                       // l=-1e8 -> inf
    float p = __builtin_amdgcn_rcpf(1.0f + e);  // -> 0 on diagonal
    unsigned n = (unsigned)blk * 128u + (unsigned)j;
    unsigned bits = threefry_bits(0u, n);
    float u = __uint_as_float((bits >> 9) | 0x3f800000u) - 1.0f;
    float smp = (u < p) ? 1.0f : 0.0f;
    float sp_pos = softplus_f(l);
    float sp_neg = softplus_f(-l);
    float ent = p * sp_neg + (1.0f - p) * sp_pos;
    size_t idx = (size_t)blk * Ln + j;
    out[OFF_MASK + idx] = l;
    out[OFF_SMP + idx] = smp;
    out[OFF_ENT + idx] = ent;
    atomicAdd(&out[OFF_GRAPH + i * Ln + j], smp * 0.0625f);
    ent_v = ent;
    lse_v = sp_pos - l * smp;
  }

  // reduce ent_v/lse_v over the two active waves
  if (t < Ln) {
#pragma unroll
    for (int off = 32; off > 0; off >>= 1) {
      ent_v += __shfl_down(ent_v, off);
      lse_v += __shfl_down(lse_v, off);
    }
    if ((t & 63) == 0) {
      redS[(t >> 6) * 2 + 0] = ent_v;
      redS[(t >> 6) * 2 + 1] = lse_v;
    }
  }
  __syncthreads();
  if (t == 0) {
    atomicAdd(&ws_acc[b], (double)(redS[0] + redS[2]));
    atomicAdd(&ws_acc[16], (double)(redS[1] + redS[3]));
  }
}

__global__ void finalize_kernel(const double* __restrict__ ws_acc, float* __restrict__ out) {
  int t = threadIdx.x;
  if (t == 0) out[OFF_LSE] = (float)(ws_acc[16] / (double)(Bn * Ln * Ln));
  if (t < Bn) out[OFF_EREG + t] = (float)(ws_acc[t] / (double)(Ln * Ln));
}

extern "C" void kernel_launch(void* const* d_in, const int* in_sizes, int n_in,
                              void* d_out, int out_size, void* d_ws, size_t ws_size,
                              hipStream_t stream) {
  const float* enc = (const float*)d_in[0];
  const float* Wl = (const float*)d_in[1];
  const float* Wr = (const float*)d_in[2];
  const float* U = (const float*)d_in[3];
  const float* bias = (const float*)d_in[4];
  float* out = (float*)d_out;

  // ws layout: dl (2048*256 f32), dr (2048*256 f32), accumulators (17 dbl)
  float* dl = (float*)d_ws;
  float* dr = dl + (size_t)Bn * Ln * Dn;
  double* ws_acc = (double*)(dr + (size_t)Bn * Ln * Dn);

  zero_kernel<<<64, 256, 0, stream>>>(out, ws_acc);
  proj_kernel<<<Bn * Ln / 8, Dn, 0, stream>>>(enc, Wl, Wr, dl, dr);
  pair_kernel<<<Bn * Ln, 256, 0, stream>>>(dl, dr, U, bias, out, ws_acc);
  finalize_kernel<<<1, 64, 0, stream>>>(ws_acc, out);
}

// Round 3
// 112.977 us; speedup vs baseline: 3.6218x; 1.5350x over previous
//
#include <hip/hip_runtime.h>

#define Bn 16
#define Ln 128
#define Hn 256
#define Dn 256

// Output layout (flat fp32 concat, reference return order)
#define OFF_MASK   0          // (B,L,L) 262144
#define OFF_SMP    262144     // (B,L,L) 262144
#define OFF_ENT    524288     // (B,L,L) 262144
#define OFF_GRAPH  786432     // (L,L)   16384
#define OFF_LSE    802816     // scalar
#define OFF_EREG   802817     // (B,)    16

static __device__ __forceinline__ unsigned rotl32(unsigned x, int r) {
  return (x << r) | (x >> (32 - r));
}

// Threefry-2x32, 20 rounds, key = (0,1)  [jax.random.key(1)], partitionable
// random-bits path: counter = (hi=0, lo=flat_index), output = y0 ^ y1.
static __device__ __forceinline__ unsigned threefry_bits(unsigned c_hi, unsigned c_lo) {
  const unsigned ks0 = 0u, ks1 = 1u;
  const unsigned ks2 = 0u ^ 1u ^ 0x1BD11BDAu;
  unsigned x0 = c_hi + ks0;
  unsigned x1 = c_lo + ks1;
  x0 += x1; x1 = rotl32(x1, 13); x1 ^= x0;
  x0 += x1; x1 = rotl32(x1, 15); x1 ^= x0;
  x0 += x1; x1 = rotl32(x1, 26); x1 ^= x0;
  x0 += x1; x1 = rotl32(x1, 6);  x1 ^= x0;
  x0 += ks1; x1 += ks2 + 1u;
  x0 += x1; x1 = rotl32(x1, 17); x1 ^= x0;
  x0 += x1; x1 = rotl32(x1, 29); x1 ^= x0;
  x0 += x1; x1 = rotl32(x1, 16); x1 ^= x0;
  x0 += x1; x1 = rotl32(x1, 24); x1 ^= x0;
  x0 += ks2; x1 += ks0 + 2u;
  x0 += x1; x1 = rotl32(x1, 13); x1 ^= x0;
  x0 += x1; x1 = rotl32(x1, 15); x1 ^= x0;
  x0 += x1; x1 = rotl32(x1, 26); x1 ^= x0;
  x0 += x1; x1 = rotl32(x1, 6);  x1 ^= x0;
  x0 += ks0; x1 += ks1 + 3u;
  x0 += x1; x1 = rotl32(x1, 17); x1 ^= x0;
  x0 += x1; x1 = rotl32(x1, 29); x1 ^= x0;
  x0 += x1; x1 = rotl32(x1, 16); x1 ^= x0;
  x0 += x1; x1 = rotl32(x1, 24); x1 ^= x0;
  x0 += ks1; x1 += ks2 + 4u;
  x0 += x1; x1 = rotl32(x1, 13); x1 ^= x0;
  x0 += x1; x1 = rotl32(x1, 15); x1 ^= x0;
  x0 += x1; x1 = rotl32(x1, 26); x1 ^= x0;
  x0 += x1; x1 = rotl32(x1, 6);  x1 ^= x0;
  x0 += ks2; x1 += ks0 + 5u;
  return x0 ^ x1;
}

static __device__ __forceinline__ float softplus_f(float x) {
  // max(x,0) + log1p(exp(-|x|)); exact at |x|=1e8 (exp(-1e8)=0)
  return fmaxf(x, 0.0f) + log1pf(__expf(-fabsf(x)));
}

static __device__ __forceinline__ float fast_tanh(float x) {
  // tanh(x) = 2/(1+e^{-2x}) - 1; saturates correctly for |x| large
  float e = __expf(-2.0f * x);
  float r = __builtin_amdgcn_rcpf(1.0f + e);
  return fmaf(2.0f, r, -1.0f);
}

// fp32 projections, 4 rows per block (512 blocks = 2 blocks/CU), with
// graph/accumulator zeroing fused in. fma order (h ascending) identical to R2.
__global__ void proj_kernel(const float* __restrict__ enc,
                            const float* __restrict__ Wl,
                            const float* __restrict__ Wr,
                            float* __restrict__ dl,
                            float* __restrict__ dr,
                            float* __restrict__ out,
                            double* __restrict__ ws_acc) {
  int gid = blockIdx.x * blockDim.x + threadIdx.x;
  if (gid < Ln * Ln) out[OFF_GRAPH + gid] = 0.0f;
  if (gid < 17) ws_acc[gid] = 0.0;

  int r0 = blockIdx.x * 4;     // 512 blocks x 4 rows = 2048 rows
  int d = threadIdx.x;         // 0..255
  __shared__ float encS[4][Hn];
  // 4 rows x 256 floats = 256 float4
  ((float4*)encS)[d] = ((const float4*)(enc + (size_t)r0 * Hn))[d];
  __syncthreads();

  float al[4] = {0.f, 0.f, 0.f, 0.f};
  float ar[4] = {0.f, 0.f, 0.f, 0.f};
  for (int h4 = 0; h4 < Hn / 4; ++h4) {
    float4 e[4];
#pragma unroll
    for (int r = 0; r < 4; ++r) e[r] = ((const float4*)encS[r])[h4];
#pragma unroll
    for (int q = 0; q < 4; ++q) {
      int h = h4 * 4 + q;
      float wl = Wl[h * Dn + d];
      float wr = Wr[h * Dn + d];
#pragma unroll
      for (int r = 0; r < 4; ++r) {
        float ev = (q == 0) ? e[r].x : (q == 1) ? e[r].y : (q == 2) ? e[r].z : e[r].w;
        al[r] = fmaf(ev, wl, al[r]);
        ar[r] = fmaf(ev, wr, ar[r]);
      }
    }
  }
#pragma unroll
  for (int r = 0; r < 4; ++r) {
    dl[(size_t)(r0 + r) * Dn + d] = al[r];
    dr[(size_t)(r0 + r) * Dn + d] = ar[r];
  }
}

// One block per (b, i-pair); 256 threads. Thread (dp = t&15, jj = t>>4) owns
// d-slice [dp*16, dp*16+16) for j = tile*16+jj, computing BOTH rows i0,i0+1
// (dr loads amortized 2x). 8 j-tiles (L=128). Wave's 16 consecutive lanes
// read one contiguous 1 KB dr row. No barriers in main loop.
__global__ void pair_kernel(const float* __restrict__ dl,
                            const float* __restrict__ dr,
                            const float* __restrict__ U,
                            const float* __restrict__ bias,
                            float* __restrict__ out,
                            double* __restrict__ ws_acc) {
  int blk = blockIdx.x;          // b*64 + ipair
  int b = blk >> 6;
  int i0 = (blk & 63) * 2;
  int t = threadIdx.x;
  int dp = t & 15;               // d-chunk
  int jj = t >> 4;               // j-slot in tile

  __shared__ float pS[2][8 * 256];   // [row][tile*256 + dp*16 + jj]
  __shared__ float redS[8];

  // register-cache dl chunks for both rows + U chunk
  float dlr0[16], dlr1[16], Ur[16];
  {
    const float4* dl40 = (const float4*)(dl + (size_t)(b * Ln + i0) * Dn + dp * 16);
    const float4* dl41 = (const float4*)(dl + (size_t)(b * Ln + i0 + 1) * Dn + dp * 16);
    const float4* U4 = (const float4*)(U + dp * 16);
#pragma unroll
    for (int q = 0; q < 4; ++q) {
      float4 a = dl40[q];
      float4 c = dl41[q];
      float4 u = U4[q];
      dlr0[4*q+0] = a.x; dlr0[4*q+1] = a.y; dlr0[4*q+2] = a.z; dlr0[4*q+3] = a.w;
      dlr1[4*q+0] = c.x; dlr1[4*q+1] = c.y; dlr1[4*q+2] = c.z; dlr1[4*q+3] = c.w;
      Ur[4*q+0] = u.x;   Ur[4*q+1] = u.y;   Ur[4*q+2] = u.z;   Ur[4*q+3] = u.w;
    }
  }

  const float* drt = dr + (size_t)b * Ln * Dn + (size_t)jj * Dn + dp * 16;
#pragma unroll
  for (int tl = 0; tl < 8; ++tl) {
    const float4* drp = (const float4*)(drt + (size_t)tl * 16 * Dn);
    float a0 = 0.0f, a1 = 0.0f;
#pragma unroll
    for (int q = 0; q < 4; ++q) {
      float4 v = drp[q];
      a0 = fmaf(fast_tanh(dlr0[4*q+0] + v.x), Ur[4*q+0], a0);
      a0 = fmaf(fast_tanh(dlr0[4*q+1] + v.y), Ur[4*q+1], a0);
      a0 = fmaf(fast_tanh(dlr0[4*q+2] + v.z), Ur[4*q+2], a0);
      a0 = fmaf(fast_tanh(dlr0[4*q+3] + v.w), Ur[4*q+3], a0);
      a1 = fmaf(fast_tanh(dlr1[4*q+0] + v.x), Ur[4*q+0], a1);
      a1 = fmaf(fast_tanh(dlr1[4*q+1] + v.y), Ur[4*q+1], a1);
      a1 = fmaf(fast_tanh(dlr1[4*q+2] + v.z), Ur[4*q+2], a1);
      a1 = fmaf(fast_tanh(dlr1[4*q+3] + v.w), Ur[4*q+3], a1);
    }
    pS[0][tl * 256 + dp * 16 + jj] = a0;
    pS[1][tl * 256 + dp * 16 + jj] = a1;
  }
  __syncthreads();

  // epilogue: all 256 threads active; thread -> (row = t>>7, j = t&127)
  int row = t >> 7;
  int j = t & 127;
  const float* ps = &pS[row][(j >> 4) * 256 + (j & 15)];
  float tot = 0.0f;
#pragma unroll
  for (int k = 0; k < 16; ++k) tot += ps[k * 16];
  int i = i0 + row;
  float l = tot + bias[0] - ((j == i) ? 1.0e8f : 0.0f);
  float e = __expf(-l);                       // l=-1e8 -> inf
  float p = __builtin_amdgcn_rcpf(1.0f + e);  // -> 0 on diagonal
  unsigned n = ((unsigned)(b * Ln + i) << 7) | (unsigned)j;
  unsigned bits = threefry_bits(0u, n);
  float u = __uint_as_float((bits >> 9) | 0x3f800000u) - 1.0f;
  float smp = (u < p) ? 1.0f : 0.0f;
  float sp_pos = softplus_f(l);
  float sp_neg = softplus_f(-l);
  float ent = p * sp_neg + (1.0f - p) * sp_pos;
  size_t idx = (size_t)(b * Ln + i) * Ln + j;
  out[OFF_MASK + idx] = l;
  out[OFF_SMP + idx] = smp;
  out[OFF_ENT + idx] = ent;
  atomicAdd(&out[OFF_GRAPH + i * Ln + j], smp * 0.0625f);
  float ent_v = ent;
  float lse_v = sp_pos - l * smp;

  // reduce over the 4 waves (all lanes valid)
#pragma unroll
  for (int off = 32; off > 0; off >>= 1) {
    ent_v += __shfl_down(ent_v, off);
    lse_v += __shfl_down(lse_v, off);
  }
  if ((t & 63) == 0) {
    redS[(t >> 6) * 2 + 0] = ent_v;
    redS[(t >> 6) * 2 + 1] = lse_v;
  }
  __syncthreads();
  if (t == 0) {
    float es = redS[0] + redS[2] + redS[4] + redS[6];
    float ls = redS[1] + redS[3] + redS[5] + redS[7];
    atomicAdd(&ws_acc[b], (double)es);
    atomicAdd(&ws_acc[16], (double)ls);
  }
}

__global__ void finalize_kernel(const double* __restrict__ ws_acc, float* __restrict__ out) {
  int t = threadIdx.x;
  if (t == 0) out[OFF_LSE] = (float)(ws_acc[16] / (double)(Bn * Ln * Ln));
  if (t < Bn) out[OFF_EREG + t] = (float)(ws_acc[t] / (double)(Ln * Ln));
}

extern "C" void kernel_launch(void* const* d_in, const int* in_sizes, int n_in,
                              void* d_out, int out_size, void* d_ws, size_t ws_size,
                              hipStream_t stream) {
  const float* enc = (const float*)d_in[0];
  const float* Wl = (const float*)d_in[1];
  const float* Wr = (const float*)d_in[2];
  const float* U = (const float*)d_in[3];
  const float* bias = (const float*)d_in[4];
  float* out = (float*)d_out;

  // ws layout: dl (2048*256 f32), dr (2048*256 f32), accumulators (17 dbl)
  float* dl = (float*)d_ws;
  float* dr = dl + (size_t)Bn * Ln * Dn;
  double* ws_acc = (double*)(dr + (size_t)Bn * Ln * Dn);

  proj_kernel<<<Bn * Ln / 4, 256, 0, stream>>>(enc, Wl, Wr, dl, dr, out, ws_acc);
  pair_kernel<<<Bn * Ln / 2, 256, 0, stream>>>(dl, dr, U, bias, out, ws_acc);
  finalize_kernel<<<1, 64, 0, stream>>>(ws_acc, out);
}